// Round 14
// baseline (2851.646 us; speedup 1.0000x reference)
//
#include <hip/hip_runtime.h>

// SineNet: fc1 -> LSTM(sine) -> proj.  B=64 T=1024 I=128 H=512 4H=2048 NS=32
// Round 14: single-barrier step = R9 + in-wave gate gather (R11 fixed).
//  - 16 gangs x 16 WGs, 4 batches/gang; R9 tagged-packet protocol verbatim
//    (pkt {f16 h|(t+1)<<16}, sc0 sc1, ring depth 2, hpub memset per launch).
//  - Gate-interleaved cols (R11 map): wave wv owns units [4wv,4wv+4);
//    col l15 = 4*ul + gate. After 16 MFMA, redistribute via 16 shfl +
//    l4-select: lane (l4=b, l15=4ul) gets all 4 gates of (b, unit).
//  - Cell: 128 lanes, 1 cell each (R9 parallelism); publish: 128 coalesced
//    dword stores (R9 addresses). R11's scatter/VALU-concentration fixed.
//  - B1 + gat_s deleted -> ONE __syncthreads per step (B3).
//  - pre_s wave-local ([2][2][4][4][36], writer wave == reader wave).

constexpr int Bb = 64;
constexpr int Tt = 1024;
constexpr int Ii = 128;
constexpr int Hh = 512;
constexpr int G4 = 2048;
constexpr int NS = 32;
constexpr int NG = 16;   // gangs
constexpr int GW = 16;   // WGs per gang
constexpr int BPG = 4;   // batches per gang

typedef _Float16 h2 __attribute__((ext_vector_type(2)));
typedef _Float16 h8 __attribute__((ext_vector_type(8)));
typedef float    f4 __attribute__((ext_vector_type(4)));
typedef unsigned int u32;
typedef u32 u32x2 __attribute__((ext_vector_type(2)));
typedef u32 u32x4 __attribute__((ext_vector_type(4)));

__device__ __forceinline__ float dot8(h8 w, h8 x, float acc) {
  h2 w0 = {w[0], w[1]}, w1 = {w[2], w[3]}, w2 = {w[4], w[5]}, w3 = {w[6], w[7]};
  h2 x0 = {x[0], x[1]}, x1 = {x[2], x[3]}, x2 = {x[4], x[5]}, x3 = {x[6], x[7]};
  acc = __builtin_amdgcn_fdot2(x0, w0, acc, false);
  acc = __builtin_amdgcn_fdot2(x1, w1, acc, false);
  acc = __builtin_amdgcn_fdot2(x2, w2, acc, false);
  acc = __builtin_amdgcn_fdot2(x3, w3, acc, false);
  return acc;
}

__device__ __forceinline__ float sigf(float x) { return 1.f / (1.f + __expf(-x)); }

// Col map: WG ss owns units [32ss,32ss+32); wave wv owns units [4wv,4wv+4).
// col16 = l15 = ul*4 + gate; global col = gate*512 + ss*32 + wv*4 + ul.

// ---- Wc = W1@W_ih (fp32) -> f16 B-frags (gate-interleaved, R11) -----------
__global__ void k_wc(const float* __restrict__ W1, const float* __restrict__ Wih,
                     const float* __restrict__ b1, const float* __restrict__ bl,
                     _Float16* __restrict__ Wc4, float* __restrict__ bias2) {
  const int j = blockIdx.x;   // global gate col 0..2047
  const int i = threadIdx.x;  // k index 0..127
  __shared__ float col[Hh];
  __shared__ float part[128];
  for (int k = i; k < Hh; k += 128) col[k] = Wih[k * G4 + j];
  __syncthreads();
  float s = 0.f;
  for (int k = i; k < Hh; k += 128) s += b1[k] * col[k];
  part[i] = s;
  __syncthreads();
  if (i == 0) {
    float t = bl[j];
    for (int k = 0; k < 128; k++) t += part[k];
    bias2[j] = t;
  }
  float acc = 0.f;
  const float* w1r = W1 + i * Hh;
#pragma unroll 4
  for (int k = 0; k < Hh; k++) acc += w1r[k] * col[k];
  const int gate = j >> 9, r = j & 511, ss = r >> 5, u = r & 31;
  const int wv = u >> 2, ul = u & 3;
  const int l15 = ul * 4 + gate;
  const int ks4 = i >> 5, l4 = (i >> 3) & 3, e = i & 7;
  Wc4[((ss * 8 + wv) * 4 + ks4) * 512 + (l4 * 16 + l15) * 8 + e] = (_Float16)acc;
}

// ---- W_hh (fp32 [512][2048]) -> f16 B-frags (gate-interleaved, R11) -------
__global__ void k_whh(const float* __restrict__ W, _Float16* __restrict__ W4) {
  const int id = blockIdx.x * 256 + threadIdx.x;  // < 131072
  const int lane = id & 63, ks = (id >> 6) & 15, wv = (id >> 10) & 7, ss = id >> 13;
  const int l15 = lane & 15, gate = l15 & 3, ul = l15 >> 2;
  const int colg = gate * 512 + ss * 32 + wv * 4 + ul;
  h8 o;
#pragma unroll
  for (int e = 0; e < 8; ++e)
    o[e] = (_Float16)W[(ks * 32 + (lane >> 4) * 8 + e) * G4 + colg];
  *(h8*)(W4 + ((ss * 8 + wv) * 16 + ks) * 512 + lane * 8) = o;
}

// ---- persistent scan: 256 WGs = 16 gangs of 16 ----------------------------
__global__ __launch_bounds__(512, 1) void k_scan(
    const float* __restrict__ x, const _Float16* __restrict__ Wc4,
    const float* __restrict__ bias2, const _Float16* __restrict__ Whh4,
    const float* __restrict__ Wo, const float* __restrict__ bo,
    float* __restrict__ out, char* __restrict__ hpub) {
  const int gid = blockIdx.x >> 4, ss = blockIdx.x & 15;
  const int tid = threadIdx.x;
  const int lane = tid & 63, wv = tid >> 6;
  const int l15 = lane & 15, l4 = lane >> 4;
  const int ul = l15 >> 2;
  const bool cellLane = ((l15 & 3) == 0);   // 16 lanes/wave: (batch=l4, unit=4wv+ul)
  const int unitW = wv * 4 + ul;            // WG-local unit 0..31
  const int gunit = ss * 32 + unitW;        // global unit

  __shared__ __align__(16) char hls[2][16384];  // h [16 rows][512] f16, (row<<4) XOR swizzle
  __shared__ __align__(16) char xws[4096];      // x window [8 rows][128] f16 swizzled
  __shared__ __align__(16) char wots[32768];    // Wo^T [32][512] f16 swizzled
  __shared__ float pre_s[2][2][4][4][36];       // [buf][tt][b][gate][unitW] (wave-local)
  __shared__ float op_s[32][17];

  // ---- register weights ----------------------------------------------------
  h8 bW[16], bC[4];
#pragma unroll
  for (int ks = 0; ks < 16; ++ks)
    bW[ks] = *(const h8*)(Whh4 + ((ss * 8 + wv) * 16 + ks) * 512 + lane * 8);
#pragma unroll
  for (int ks = 0; ks < 4; ++ks)
    bC[ks] = *(const h8*)(Wc4 + ((ss * 8 + wv) * 4 + ks) * 512 + lane * 8);

  float bIr = 0.f, bFr = 0.f, bGr = 0.f, bOr = 0.f;
  if (cellLane) {
    bIr = bias2[gunit];        bFr = bias2[512 + gunit];
    bGr = bias2[1024 + gunit]; bOr = bias2[1536 + gunit];
  }
  float c_ = 0.f;  // cell state for (batch=l4, unit)
  const int nn = tid & 31, pp = tid >> 5;  // out-proj role
  const float bor = (tid < NS) ? bo[tid] : 0.f;

  // ---- init LDS: zero both hls buffers + xws, stage Wo^T -------------------
#pragma unroll
  for (int q = 0; q < 2; ++q) {
    u32x4 z = {0, 0, 0, 0};
    *(u32x4*)(hls[0] + (q * 512 + tid) * 16) = z;
    *(u32x4*)(hls[1] + (q * 512 + tid) * 16) = z;
  }
  if (tid < 256) { u32x4 z = {0, 0, 0, 0}; *(u32x4*)(xws + tid * 16) = z; }
  for (int it = tid; it < Hh * NS; it += 512) {
    int k = it >> 5, n = it & 31;
    *(_Float16*)(wots + n * 1024 + ((2 * k) ^ ((n & 7) << 4))) = (_Float16)Wo[k * NS + n];
  }

  auto stage_x = [&](int t0) {  // rows tt*4+b of [8][128] f16
    if (tid < 128) {
      const int row = tid >> 4, cc = tid & 15;
      const float* src = x + ((size_t)(gid * BPG + (row & 3)) * Tt + t0 + (row >> 2)) * Ii + cc * 8;
      f4 s0 = *(const f4*)src, s1 = *(const f4*)(src + 4);
      h8 v = {(_Float16)s0[0], (_Float16)s0[1], (_Float16)s0[2], (_Float16)s0[3],
              (_Float16)s1[0], (_Float16)s1[1], (_Float16)s1[2], (_Float16)s1[3]};
      *(h8*)(xws + row * 256 + ((cc * 16) ^ ((row & 7) << 4))) = v;
    }
  };
  auto do_pregate = [&](int buf) {  // wave's 16 (unit,gate) cols; C rows 0-7
    f4 pa = {0.f, 0.f, 0.f, 0.f};
#pragma unroll
    for (int ks = 0; ks < 4; ++ks) {
      const int row = l15;
      h8 a = *(const h8*)(xws + row * 256 + ((ks * 64 + l4 * 16) ^ ((row & 7) << 4)));
      pa = __builtin_amdgcn_mfma_f32_16x16x32_f16(a, bC[ks], pa, 0, 0, 0);
    }
    if (l4 < 2) {  // tt = l4, batch = e, gate = l15&3, unit = unitW
#pragma unroll
      for (int e = 0; e < 4; ++e)
        pre_s[buf][l4][e][l15 & 3][unitW] = pa[e];
    }
  };
  auto op_part = [&](const char* hb) {  // WGs ss<4: partials of h[row ss] @ Wo
    if (ss < BPG) {
      float acc = 0.f;
#pragma unroll
      for (int q = 0; q < 4; ++q) {
        h8 w_ = *(const h8*)(wots + nn * 1024 + ((pp * 64 + q * 16) ^ ((nn & 7) << 4)));
        h8 hv = *(const h8*)(hb + ss * 1024 + ((pp * 64 + q * 16) ^ (ss << 4)));
        acc = dot8(w_, hv, acc);
      }
      op_s[nn][pp] = acc;
    }
  };

  stage_x(0);
  __syncthreads();
  do_pregate(0);  // steps 0,1

  int cur = 0;
#pragma unroll 1
  for (int t = 0; t < Tt; ++t) {
    char* const hpg = hpub + gid * 16384 + (t & 1) * 8192;
    const char* const hc = hls[cur];
    char* const hn_ = hls[cur ^ 1];
    // ---- gate GEMM: wave's 16 (unit,gate) cols, K=512 ---------------------
    f4 g0 = {0.f, 0.f, 0.f, 0.f}, g1 = {0.f, 0.f, 0.f, 0.f};
#pragma unroll
    for (int ks = 0; ks < 16; ++ks) {
      const int row = l15;
      h8 a = *(const h8*)(hc + row * 1024 + ((ks * 64 + l4 * 16) ^ (row << 4)));
      if (ks & 1) g1 = __builtin_amdgcn_mfma_f32_16x16x32_f16(a, bW[ks], g1, 0, 0, 0);
      else        g0 = __builtin_amdgcn_mfma_f32_16x16x32_f16(a, bW[ks], g0, 0, 0, 0);
    }
    f4 gs;
#pragma unroll
    for (int e = 0; e < 4; ++e) gs[e] = g0[e] + g1[e];
    // ---- redistribute: lane (l4=b, l15=4ul) <- gate g from lane l15+g -----
    float ag[4];
#pragma unroll
    for (int g = 0; g < 4; ++g) {
      float t0 = __shfl(gs[0], l15 + g);
      float t1 = __shfl(gs[1], l15 + g);
      float t2 = __shfl(gs[2], l15 + g);
      float t3 = __shfl(gs[3], l15 + g);
      ag[g] = (l4 == 0) ? t0 : (l4 == 1) ? t1 : (l4 == 2) ? t2 : t3;
    }
    // ---- cell + coalesced tagged publish (no barrier since GEMM) ----------
    if (cellLane) {
      const int ph = (t >> 1) & 1, tt = t & 1;
      float aI = ag[0] + pre_s[ph][tt][l4][0][unitW] + bIr;
      float aF = ag[1] + pre_s[ph][tt][l4][1][unitW] + bFr;
      float aG = ag[2] + pre_s[ph][tt][l4][2][unitW] + bGr;
      float aO = ag[3] + pre_s[ph][tt][l4][3][unitW] + bOr;
      float iv = sigf(aI), fv = sigf(aF), gv = __sinf(aG), ov = sigf(aO);
      c_ = fv * c_ + iv * gv;
      float hnv = ov * __sinf(c_);
      _Float16 hf = (_Float16)hnv;
      u32 pkt = (u32)__builtin_bit_cast(unsigned short, hf) | ((u32)(t + 1) << 16);
      u32* dst = (u32*)(hpg + ((size_t)(l4 * 512 + gunit)) * 4);
      asm volatile("global_store_dword %0, %1, off sc0 sc1" :: "v"(dst), "v"(pkt) : "memory");
    }
    // ---- shadow (no remote deps) -----------------------------------------
    if (!(t & 1)) { if (t <= 1020) stage_x(t + 2); }
    else if (t <= 1021) do_pregate(((t + 1) >> 1) & 1);
    if (t > 0) op_part(hc);  // partials for out[t-1] from h_{t-1}
    // ---- poll own 4 packets, restage into hls[cur^1] (R9 verbatim) --------
    {
      const u32* sp = (const u32*)(hpg + (size_t)tid * 16);
      const u32 want = (u32)(t + 1);
      u32x4 v;
      while (true) {
        asm volatile("global_load_dwordx4 %0, %1, off sc0 sc1\ns_waitcnt vmcnt(0)"
                     : "=v"(v) : "v"(sp) : "memory");
        if ((v[0] >> 16) == want && (v[1] >> 16) == want &&
            (v[2] >> 16) == want && (v[3] >> 16) == want) break;
      }
      __builtin_amdgcn_sched_barrier(0);
      u32x2 d = {(v[0] & 0xFFFFu) | (v[1] << 16), (v[2] & 0xFFFFu) | (v[3] << 16)};
      const int b = tid >> 7, k = tid & 127;
      *(u32x2*)(hn_ + b * 1024 + ((k * 8) ^ (b << 4))) = d;
    }
    __syncthreads();  // B3 (the only barrier): hls[cur^1] = h_t; op_s ready
    if (t > 0 && ss < BPG && tid < NS) {
      float s_ = bor;
#pragma unroll
      for (int p = 0; p < 16; ++p) s_ += op_s[tid][p];
      out[((size_t)(gid * BPG + ss) * Tt + (t - 1)) * NS + tid] = s_;
    }
    cur ^= 1;
  }
  // epilogue: out[1023] from h_1023 = hls[cur]
  op_part(hls[cur]);
  __syncthreads();
  if (ss < BPG && tid < NS) {
    float s_ = bor;
#pragma unroll
    for (int p = 0; p < 16; ++p) s_ += op_s[tid][p];
    out[((size_t)(gid * BPG + ss) * Tt + 1023) * NS + tid] = s_;
  }
}

extern "C" void kernel_launch(void* const* d_in, const int* in_sizes, int n_in,
                              void* d_out, int out_size, void* d_ws, size_t ws_size,
                              hipStream_t stream) {
  const float* x   = (const float*)d_in[0];
  const float* W1  = (const float*)d_in[1];
  const float* b1  = (const float*)d_in[2];
  const float* Wih = (const float*)d_in[3];
  const float* Whh = (const float*)d_in[4];
  const float* bl  = (const float*)d_in[5];
  const float* Wo  = (const float*)d_in[6];
  const float* bo  = (const float*)d_in[7];
  float* out = (float*)d_out;

  char* ws = (char*)d_ws;
  _Float16* Wc4   = (_Float16*)(ws);            // 512 KB
  float*    bias2 = (float*)(ws + 524288);      // 8 KB
  _Float16* Whh4  = (_Float16*)(ws + 532480);   // 2 MB
  char*     hpub  = ws + 2629632;               // 256 KB (16 gangs x 2 slots x 8KB)

  (void)hipMemsetAsync(hpub, 0, 262144, stream);  // kill stale tags (replay safety)
  k_wc<<<G4, 128, 0, stream>>>(W1, Wih, b1, bl, Wc4, bias2);
  k_whh<<<512, 256, 0, stream>>>(Whh, Whh4);
  k_scan<<<256, 512, 0, stream>>>(x, Wc4, bias2, Whh4, Wo, bo, out, hpub);
}

// Round 15
// 2402.017 us; speedup vs baseline: 1.1872x; 1.1872x over previous
//
#include <hip/hip_runtime.h>

// SineNet: fc1 -> LSTM(sine) -> proj.  B=64 T=1024 I=128 H=512 4H=2048 NS=32
// Round 15: R9 verbatim + PIPELINED poll (4 in-flight loads, counted waits).
//  - 16 gangs x 16 WGs, 4 batches/gang; tagged-packet protocol (pkt =
//    {f16 h | (t+1)<<16}, sc0 sc1, ring depth 2, hpub memset per launch).
//  - Poll change only: instead of load->vmcnt(0)->check (detection quantized
//    to a full LLC RT per retry), keep 4 loads to the tag line in flight and
//    check in issue order with vmcnt(3/2/1/0) -> sampling interval ~50cyc.
//    One vmcnt(0) drain before the loop makes the counts exact (no other
//    VMEM inside). sched_barrier(0) after each waitcnt (reorder guard).
//  - Everything else (publish, shadow, restage, barriers B1/B3, layouts,
//    k_wc, k_whh) is R9 byte-for-byte.

constexpr int Bb = 64;
constexpr int Tt = 1024;
constexpr int Ii = 128;
constexpr int Hh = 512;
constexpr int G4 = 2048;
constexpr int NS = 32;
constexpr int NG = 16;   // gangs
constexpr int GW = 16;   // WGs per gang
constexpr int BPG = 4;   // batches per gang

typedef _Float16 h2 __attribute__((ext_vector_type(2)));
typedef _Float16 h8 __attribute__((ext_vector_type(8)));
typedef float    f4 __attribute__((ext_vector_type(4)));
typedef unsigned int u32;
typedef u32 u32x2 __attribute__((ext_vector_type(2)));
typedef u32 u32x4 __attribute__((ext_vector_type(4)));

__device__ __forceinline__ float dot8(h8 w, h8 x, float acc) {
  h2 w0 = {w[0], w[1]}, w1 = {w[2], w[3]}, w2 = {w[4], w[5]}, w3 = {w[6], w[7]};
  h2 x0 = {x[0], x[1]}, x1 = {x[2], x[3]}, x2 = {x[4], x[5]}, x3 = {x[6], x[7]};
  acc = __builtin_amdgcn_fdot2(x0, w0, acc, false);
  acc = __builtin_amdgcn_fdot2(x1, w1, acc, false);
  acc = __builtin_amdgcn_fdot2(x2, w2, acc, false);
  acc = __builtin_amdgcn_fdot2(x3, w3, acc, false);
  return acc;
}

__device__ __forceinline__ float sigf(float x) { return 1.f / (1.f + __expf(-x)); }

__device__ __forceinline__ bool tagok(u32x4 v, u32 want) {
  return (v[0] >> 16) == want && (v[1] >> 16) == want &&
         (v[2] >> 16) == want && (v[3] >> 16) == want;
}

// WG ss owns units [32ss,32ss+32). Per-WG col c128 = gate*32+u (0..127);
// col-block cb = c128>>4 (one per wave); global col = gate*512 + ss*32 + u.

// ---- Wc = W1@W_ih (fp32) -> f16 B-frags; bias2 = b1@W_ih + b_lstm ---------
__global__ void k_wc(const float* __restrict__ W1, const float* __restrict__ Wih,
                     const float* __restrict__ b1, const float* __restrict__ bl,
                     _Float16* __restrict__ Wc4, float* __restrict__ bias2) {
  const int j = blockIdx.x;   // global gate col 0..2047
  const int i = threadIdx.x;  // k index 0..127
  __shared__ float col[Hh];
  __shared__ float part[128];
  for (int k = i; k < Hh; k += 128) col[k] = Wih[k * G4 + j];
  __syncthreads();
  float s = 0.f;
  for (int k = i; k < Hh; k += 128) s += b1[k] * col[k];
  part[i] = s;
  __syncthreads();
  if (i == 0) {
    float t = bl[j];
    for (int k = 0; k < 128; k++) t += part[k];
    bias2[j] = t;
  }
  float acc = 0.f;
  const float* w1r = W1 + i * Hh;
#pragma unroll 4
  for (int k = 0; k < Hh; k++) acc += w1r[k] * col[k];
  const int gate = j >> 9, r = j & 511, ss = r >> 5, u = r & 31;
  const int c128 = gate * 32 + u, cb = c128 >> 4, c = c128 & 15;
  const int lane = ((i >> 3) & 3) * 16 + c, ks4 = i >> 5, e = i & 7;
  Wc4[((ss * 8 + cb) * 4 + ks4) * 512 + lane * 8 + e] = (_Float16)acc;
}

// ---- W_hh (fp32 [512][2048]) -> f16 B-frags -------------------------------
__global__ void k_whh(const float* __restrict__ W, _Float16* __restrict__ W4) {
  const int id = blockIdx.x * 256 + threadIdx.x;  // < 131072
  const int lane = id & 63, ks = (id >> 6) & 15, cb = (id >> 10) & 7, ss = id >> 13;
  const int c = lane & 15, c128 = cb * 16 + c;
  const int gate = c128 >> 5, u = c128 & 31;
  const int colg = gate * 512 + ss * 32 + u;
  h8 o;
#pragma unroll
  for (int e = 0; e < 8; ++e)
    o[e] = (_Float16)W[(ks * 32 + (lane >> 4) * 8 + e) * G4 + colg];
  *(h8*)(W4 + ((ss * 8 + cb) * 16 + ks) * 512 + lane * 8) = o;
}

// ---- persistent scan: 256 WGs = 16 gangs of 16 ----------------------------
__global__ __launch_bounds__(512, 1) void k_scan(
    const float* __restrict__ x, const _Float16* __restrict__ Wc4,
    const float* __restrict__ bias2, const _Float16* __restrict__ Whh4,
    const float* __restrict__ Wo, const float* __restrict__ bo,
    float* __restrict__ out, char* __restrict__ hpub) {
  const int gid = blockIdx.x >> 4, ss = blockIdx.x & 15;
  const int tid = threadIdx.x;
  const int lane = tid & 63, wv = tid >> 6;
  const int l15 = lane & 15, l4 = lane >> 4;

  __shared__ __align__(16) char hls[2][16384];  // h [16 rows][512] f16, (row<<4) XOR swizzle
  __shared__ __align__(16) char xws[4096];      // x window [8 rows][128] f16 swizzled (rows 8-15 zero)
  __shared__ __align__(16) char wots[32768];    // Wo^T [32][512] f16 swizzled
  __shared__ __align__(16) float pre_s[2][2][4][4][33];  // [buf][tt][b][gate][u]
  __shared__ float gat_s[4][4][33];             // [b][gate][u]
  __shared__ float op_s[32][17];

  // ---- register weights: wave wv owns col-block cb = wv --------------------
  h8 bW[16], bC[4];
#pragma unroll
  for (int ks = 0; ks < 16; ++ks)
    bW[ks] = *(const h8*)(Whh4 + ((ss * 8 + wv) * 16 + ks) * 512 + lane * 8);
#pragma unroll
  for (int ks = 0; ks < 4; ++ks)
    bC[ks] = *(const h8*)(Wc4 + ((ss * 8 + wv) * 4 + ks) * 512 + lane * 8);

  const int b8 = tid >> 5, ml = tid & 31;  // cell role (tid<128): batch, unit
  const float bI = bias2[ss * 32 + ml],        bF = bias2[512 + ss * 32 + ml],
              bG = bias2[1024 + ss * 32 + ml], bO = bias2[1536 + ss * 32 + ml];
  const int nn = tid & 31, pp = tid >> 5;  // out-proj role
  const float bor = (tid < NS) ? bo[tid] : 0.f;

  // ---- init LDS: zero both hls buffers + xws, stage Wo^T -------------------
#pragma unroll
  for (int q = 0; q < 2; ++q) {
    u32x4 z = {0, 0, 0, 0};
    *(u32x4*)(hls[0] + (q * 512 + tid) * 16) = z;
    *(u32x4*)(hls[1] + (q * 512 + tid) * 16) = z;
  }
  if (tid < 256) { u32x4 z = {0, 0, 0, 0}; *(u32x4*)(xws + tid * 16) = z; }
  for (int it = tid; it < Hh * NS; it += 512) {
    int k = it >> 5, n = it & 31;
    *(_Float16*)(wots + n * 1024 + ((2 * k) ^ ((n & 7) << 4))) = (_Float16)Wo[k * NS + n];
  }
  float c_ = 0.f;

  auto stage_x = [&](int t0) {  // rows tt*4+b of [8][128] f16
    if (tid < 128) {
      const int row = tid >> 4, cc = tid & 15;
      const float* src = x + ((size_t)(gid * BPG + (row & 3)) * Tt + t0 + (row >> 2)) * Ii + cc * 8;
      f4 s0 = *(const f4*)src, s1 = *(const f4*)(src + 4);
      h8 v = {(_Float16)s0[0], (_Float16)s0[1], (_Float16)s0[2], (_Float16)s0[3],
              (_Float16)s1[0], (_Float16)s1[1], (_Float16)s1[2], (_Float16)s1[3]};
      *(h8*)(xws + row * 256 + ((cc * 16) ^ ((row & 7) << 4))) = v;
    }
  };
  auto do_pregate = [&](int buf) {  // wave wv: its 16 cols; C rows 0-7 used
    f4 pa = {0.f, 0.f, 0.f, 0.f};
#pragma unroll
    for (int ks = 0; ks < 4; ++ks) {
      const int row = l15;
      h8 a = *(const h8*)(xws + row * 256 + ((ks * 64 + l4 * 16) ^ ((row & 7) << 4)));
      pa = __builtin_amdgcn_mfma_f32_16x16x32_f16(a, bC[ks], pa, 0, 0, 0);
    }
    if (l4 < 2) {
      const int c128 = wv * 16 + l15, gam = c128 >> 5, u = c128 & 31;
#pragma unroll
      for (int e = 0; e < 4; ++e) {
        const int row = l4 * 4 + e;  // 0..7 = tt*4 + b
        pre_s[buf][row >> 2][row & 3][gam][u] = pa[e];
      }
    }
  };
  auto op_part = [&](const char* hb) {  // WGs ss<4: partials of h[row ss] @ Wo
    if (ss < BPG) {
      float acc = 0.f;
#pragma unroll
      for (int q = 0; q < 4; ++q) {
        h8 w_ = *(const h8*)(wots + nn * 1024 + ((pp * 64 + q * 16) ^ ((nn & 7) << 4)));
        h8 hv = *(const h8*)(hb + ss * 1024 + ((pp * 64 + q * 16) ^ (ss << 4)));
        acc = dot8(w_, hv, acc);
      }
      op_s[nn][pp] = acc;
    }
  };

  stage_x(0);
  __syncthreads();
  do_pregate(0);  // steps 0,1

  int cur = 0;
#pragma unroll 1
  for (int t = 0; t < Tt; ++t) {
    char* const hpg = hpub + gid * 16384 + (t & 1) * 8192;
    const char* const hc = hls[cur];
    char* const hn_ = hls[cur ^ 1];
    // ---- gate GEMM: wave's 16 cols, K=512 ---------------------------------
    {
      f4 g0 = {0.f, 0.f, 0.f, 0.f}, g1 = {0.f, 0.f, 0.f, 0.f};
#pragma unroll
      for (int ks = 0; ks < 16; ++ks) {
        const int row = l15;
        h8 a = *(const h8*)(hc + row * 1024 + ((ks * 64 + l4 * 16) ^ (row << 4)));
        if (ks & 1) g1 = __builtin_amdgcn_mfma_f32_16x16x32_f16(a, bW[ks], g1, 0, 0, 0);
        else        g0 = __builtin_amdgcn_mfma_f32_16x16x32_f16(a, bW[ks], g0, 0, 0, 0);
      }
      if (l4 == 0) {
        const int c128 = wv * 16 + l15, gam = c128 >> 5, u = c128 & 31;
#pragma unroll
        for (int e = 0; e < 4; ++e) gat_s[e][gam][u] = g0[e] + g1[e];
      }
    }
    __syncthreads();  // B1: gat_s ready
    // ---- cell update + tagged-packet publish (R9 coalesced) ---------------
    if (tid < 128) {
      const int ph = (t >> 1) & 1, tt = t & 1;
      float aI = gat_s[b8][0][ml] + pre_s[ph][tt][b8][0][ml] + bI;
      float aF = gat_s[b8][1][ml] + pre_s[ph][tt][b8][1][ml] + bF;
      float aG = gat_s[b8][2][ml] + pre_s[ph][tt][b8][2][ml] + bG;
      float aO = gat_s[b8][3][ml] + pre_s[ph][tt][b8][3][ml] + bO;
      float iv = sigf(aI), fv = sigf(aF), gv = __sinf(aG), ov = sigf(aO);
      c_ = fv * c_ + iv * gv;
      float hnv = ov * __sinf(c_);
      _Float16 hf = (_Float16)hnv;
      u32 pkt = (u32)__builtin_bit_cast(unsigned short, hf) | ((u32)(t + 1) << 16);
      u32* dst = (u32*)(hpg + ((size_t)(b8 * 512 + ss * 32 + ml)) * 4);
      asm volatile("global_store_dword %0, %1, off sc0 sc1" :: "v"(dst), "v"(pkt) : "memory");
    }
    // ---- shadow (no remote deps) -----------------------------------------
    if (!(t & 1)) { if (t <= 1020) stage_x(t + 2); }
    else if (t <= 1021) do_pregate(((t + 1) >> 1) & 1);
    if (t > 0) op_part(hc);  // partials for out[t-1] from h_{t-1}
    // ---- PIPELINED poll: 4 in-flight loads, counted waits -----------------
    {
      const u32* sp = (const u32*)(hpg + (size_t)tid * 16);
      const u32 want = (u32)(t + 1);
      u32x4 v, v0, v1, v2, v3;
      asm volatile("s_waitcnt vmcnt(0)" ::: "memory");  // drain store/stage_x
      bool got = false;
      while (!got) {
        asm volatile("global_load_dwordx4 %0, %1, off sc0 sc1" : "=&v"(v0) : "v"(sp) : "memory");
        asm volatile("global_load_dwordx4 %0, %1, off sc0 sc1" : "=&v"(v1) : "v"(sp) : "memory");
        asm volatile("global_load_dwordx4 %0, %1, off sc0 sc1" : "=&v"(v2) : "v"(sp) : "memory");
        asm volatile("global_load_dwordx4 %0, %1, off sc0 sc1" : "=&v"(v3) : "v"(sp) : "memory");
        asm volatile("s_waitcnt vmcnt(3)" ::: "memory");
        __builtin_amdgcn_sched_barrier(0);
        if (tagok(v0, want)) { v = v0; got = true; }
        if (!got) {
          asm volatile("s_waitcnt vmcnt(2)" ::: "memory");
          __builtin_amdgcn_sched_barrier(0);
          if (tagok(v1, want)) { v = v1; got = true; }
        }
        if (!got) {
          asm volatile("s_waitcnt vmcnt(1)" ::: "memory");
          __builtin_amdgcn_sched_barrier(0);
          if (tagok(v2, want)) { v = v2; got = true; }
        }
        if (!got) {
          asm volatile("s_waitcnt vmcnt(0)" ::: "memory");
          __builtin_amdgcn_sched_barrier(0);
          if (tagok(v3, want)) { v = v3; got = true; }
        }
      }
      asm volatile("s_waitcnt vmcnt(0)" ::: "memory");  // retire leftovers
      __builtin_amdgcn_sched_barrier(0);
      u32x2 d = {(v[0] & 0xFFFFu) | (v[1] << 16), (v[2] & 0xFFFFu) | (v[3] << 16)};
      const int b = tid >> 7, k = tid & 127;
      *(u32x2*)(hn_ + b * 1024 + ((k * 8) ^ (b << 4))) = d;
    }
    __syncthreads();  // B3: hls[cur^1] = h_t; op_s ready
    if (t > 0 && ss < BPG && tid < NS) {
      float s_ = bor;
#pragma unroll
      for (int p = 0; p < 16; ++p) s_ += op_s[tid][p];
      out[((size_t)(gid * BPG + ss) * Tt + (t - 1)) * NS + tid] = s_;
    }
    cur ^= 1;
  }
  // epilogue: out[1023] from h_1023 = hls[cur]
  op_part(hls[cur]);
  __syncthreads();
  if (ss < BPG && tid < NS) {
    float s_ = bor;
#pragma unroll
    for (int p = 0; p < 16; ++p) s_ += op_s[tid][p];
    out[((size_t)(gid * BPG + ss) * Tt + 1023) * NS + tid] = s_;
  }
}

extern "C" void kernel_launch(void* const* d_in, const int* in_sizes, int n_in,
                              void* d_out, int out_size, void* d_ws, size_t ws_size,
                              hipStream_t stream) {
  const float* x   = (const float*)d_in[0];
  const float* W1  = (const float*)d_in[1];
  const float* b1  = (const float*)d_in[2];
  const float* Wih = (const float*)d_in[3];
  const float* Whh = (const float*)d_in[4];
  const float* bl  = (const float*)d_in[5];
  const float* Wo  = (const float*)d_in[6];
  const float* bo  = (const float*)d_in[7];
  float* out = (float*)d_out;

  char* ws = (char*)d_ws;
  _Float16* Wc4   = (_Float16*)(ws);            // 512 KB
  float*    bias2 = (float*)(ws + 524288);      // 8 KB
  _Float16* Whh4  = (_Float16*)(ws + 532480);   // 2 MB
  char*     hpub  = ws + 2629632;               // 256 KB (16 gangs x 2 slots x 8KB)

  (void)hipMemsetAsync(hpub, 0, 262144, stream);  // kill stale tags (replay safety)
  k_wc<<<G4, 128, 0, stream>>>(W1, Wih, b1, bl, Wc4, bias2);
  k_whh<<<512, 256, 0, stream>>>(Whh, Whh4);
  k_scan<<<256, 512, 0, stream>>>(x, Wc4, bias2, Whh4, Wo, bo, out, hpub);
}

// Round 17
// 1939.042 us; speedup vs baseline: 1.4706x; 1.2388x over previous
//
#include <hip/hip_runtime.h>

// SineNet: fc1 -> LSTM(sine) -> proj.  B=64 T=1024 I=128 H=512 4H=2048 NS=32
// Round 17: restore R9 verbatim (proven best, 1906 us). R10-R16 structural
// variants all regressed or hung; XCD-local family retired after 3 hangs.
//  - 16 gangs x 16 WGs (gang = bid>>4, placement-independent), 4 batches/gang.
//  - h published as per-unit dword packets {f16 h | (t+1)<<16} via sc0 sc1:
//    4B store is atomic -> packet self-validating -> no ack, no flag.
//  - Readers poll their own 4 packets (one dwordx4) until all tags == t+1,
//    then ds_write into double-buffered hls. Ring depth 2 is skew-safe.
//  - Replay safety: hpub memset to 0 every launch.
//  - 2 barriers/step (B1 gat_s, B3 restage); hls (row<<4) XOR swizzle.
//  - W_hh (64KB) + Wc (16KB) per WG in VGPRs (B-frags), N-split on 8 waves.

constexpr int Bb = 64;
constexpr int Tt = 1024;
constexpr int Ii = 128;
constexpr int Hh = 512;
constexpr int G4 = 2048;
constexpr int NS = 32;
constexpr int NG = 16;   // gangs
constexpr int GW = 16;   // WGs per gang
constexpr int BPG = 4;   // batches per gang

typedef _Float16 h2 __attribute__((ext_vector_type(2)));
typedef _Float16 h8 __attribute__((ext_vector_type(8)));
typedef float    f4 __attribute__((ext_vector_type(4)));
typedef unsigned int u32;
typedef u32 u32x2 __attribute__((ext_vector_type(2)));
typedef u32 u32x4 __attribute__((ext_vector_type(4)));

__device__ __forceinline__ float dot8(h8 w, h8 x, float acc) {
  h2 w0 = {w[0], w[1]}, w1 = {w[2], w[3]}, w2 = {w[4], w[5]}, w3 = {w[6], w[7]};
  h2 x0 = {x[0], x[1]}, x1 = {x[2], x[3]}, x2 = {x[4], x[5]}, x3 = {x[6], x[7]};
  acc = __builtin_amdgcn_fdot2(x0, w0, acc, false);
  acc = __builtin_amdgcn_fdot2(x1, w1, acc, false);
  acc = __builtin_amdgcn_fdot2(x2, w2, acc, false);
  acc = __builtin_amdgcn_fdot2(x3, w3, acc, false);
  return acc;
}

__device__ __forceinline__ float sigf(float x) { return 1.f / (1.f + __expf(-x)); }

// WG ss owns units [32ss,32ss+32). Per-WG col c128 = gate*32+u (0..127);
// col-block cb = c128>>4 (one per wave); global col = gate*512 + ss*32 + u.

// ---- Wc = W1@W_ih (fp32) -> f16 B-frags; bias2 = b1@W_ih + b_lstm ---------
__global__ void k_wc(const float* __restrict__ W1, const float* __restrict__ Wih,
                     const float* __restrict__ b1, const float* __restrict__ bl,
                     _Float16* __restrict__ Wc4, float* __restrict__ bias2) {
  const int j = blockIdx.x;   // global gate col 0..2047
  const int i = threadIdx.x;  // k index 0..127
  __shared__ float col[Hh];
  __shared__ float part[128];
  for (int k = i; k < Hh; k += 128) col[k] = Wih[k * G4 + j];
  __syncthreads();
  float s = 0.f;
  for (int k = i; k < Hh; k += 128) s += b1[k] * col[k];
  part[i] = s;
  __syncthreads();
  if (i == 0) {
    float t = bl[j];
    for (int k = 0; k < 128; k++) t += part[k];
    bias2[j] = t;
  }
  float acc = 0.f;
  const float* w1r = W1 + i * Hh;
#pragma unroll 4
  for (int k = 0; k < Hh; k++) acc += w1r[k] * col[k];
  const int gate = j >> 9, r = j & 511, ss = r >> 5, u = r & 31;
  const int c128 = gate * 32 + u, cb = c128 >> 4, c = c128 & 15;
  const int lane = ((i >> 3) & 3) * 16 + c, ks4 = i >> 5, e = i & 7;
  Wc4[((ss * 8 + cb) * 4 + ks4) * 512 + lane * 8 + e] = (_Float16)acc;
}

// ---- W_hh (fp32 [512][2048]) -> f16 B-frags -------------------------------
__global__ void k_whh(const float* __restrict__ W, _Float16* __restrict__ W4) {
  const int id = blockIdx.x * 256 + threadIdx.x;  // < 131072
  const int lane = id & 63, ks = (id >> 6) & 15, cb = (id >> 10) & 7, ss = id >> 13;
  const int c = lane & 15, c128 = cb * 16 + c;
  const int gate = c128 >> 5, u = c128 & 31;
  const int colg = gate * 512 + ss * 32 + u;
  h8 o;
#pragma unroll
  for (int e = 0; e < 8; ++e)
    o[e] = (_Float16)W[(ks * 32 + (lane >> 4) * 8 + e) * G4 + colg];
  *(h8*)(W4 + ((ss * 8 + cb) * 16 + ks) * 512 + lane * 8) = o;
}

// ---- persistent scan: 256 WGs = 16 gangs of 16 ----------------------------
__global__ __launch_bounds__(512, 1) void k_scan(
    const float* __restrict__ x, const _Float16* __restrict__ Wc4,
    const float* __restrict__ bias2, const _Float16* __restrict__ Whh4,
    const float* __restrict__ Wo, const float* __restrict__ bo,
    float* __restrict__ out, char* __restrict__ hpub) {
  const int gid = blockIdx.x >> 4, ss = blockIdx.x & 15;
  const int tid = threadIdx.x;
  const int lane = tid & 63, wv = tid >> 6;
  const int l15 = lane & 15, l4 = lane >> 4;

  __shared__ __align__(16) char hls[2][16384];  // h [16 rows][512] f16, (row<<4) XOR swizzle
  __shared__ __align__(16) char xws[4096];      // x window [8 rows][128] f16 swizzled (rows 8-15 zero)
  __shared__ __align__(16) char wots[32768];    // Wo^T [32][512] f16 swizzled
  __shared__ __align__(16) float pre_s[2][2][4][4][33];  // [buf][tt][b][gate][u]
  __shared__ float gat_s[4][4][33];             // [b][gate][u]
  __shared__ float op_s[32][17];

  // ---- register weights: wave wv owns col-block cb = wv --------------------
  h8 bW[16], bC[4];
#pragma unroll
  for (int ks = 0; ks < 16; ++ks)
    bW[ks] = *(const h8*)(Whh4 + ((ss * 8 + wv) * 16 + ks) * 512 + lane * 8);
#pragma unroll
  for (int ks = 0; ks < 4; ++ks)
    bC[ks] = *(const h8*)(Wc4 + ((ss * 8 + wv) * 4 + ks) * 512 + lane * 8);

  const int b8 = tid >> 5, ml = tid & 31;  // cell role (tid<128): batch, unit
  const float bI = bias2[ss * 32 + ml],        bF = bias2[512 + ss * 32 + ml],
              bG = bias2[1024 + ss * 32 + ml], bO = bias2[1536 + ss * 32 + ml];
  const int nn = tid & 31, pp = tid >> 5;  // out-proj role
  const float bor = (tid < NS) ? bo[tid] : 0.f;

  // ---- init LDS: zero both hls buffers + xws, stage Wo^T -------------------
#pragma unroll
  for (int q = 0; q < 2; ++q) {
    u32x4 z = {0, 0, 0, 0};
    *(u32x4*)(hls[0] + (q * 512 + tid) * 16) = z;
    *(u32x4*)(hls[1] + (q * 512 + tid) * 16) = z;
  }
  if (tid < 256) { u32x4 z = {0, 0, 0, 0}; *(u32x4*)(xws + tid * 16) = z; }
  for (int it = tid; it < Hh * NS; it += 512) {
    int k = it >> 5, n = it & 31;
    *(_Float16*)(wots + n * 1024 + ((2 * k) ^ ((n & 7) << 4))) = (_Float16)Wo[k * NS + n];
  }
  float c_ = 0.f;

  auto stage_x = [&](int t0) {  // rows tt*4+b of [8][128] f16
    if (tid < 128) {
      const int row = tid >> 4, cc = tid & 15;
      const float* src = x + ((size_t)(gid * BPG + (row & 3)) * Tt + t0 + (row >> 2)) * Ii + cc * 8;
      f4 s0 = *(const f4*)src, s1 = *(const f4*)(src + 4);
      h8 v = {(_Float16)s0[0], (_Float16)s0[1], (_Float16)s0[2], (_Float16)s0[3],
              (_Float16)s1[0], (_Float16)s1[1], (_Float16)s1[2], (_Float16)s1[3]};
      *(h8*)(xws + row * 256 + ((cc * 16) ^ ((row & 7) << 4))) = v;
    }
  };
  auto do_pregate = [&](int buf) {  // wave wv: its 16 cols; C rows 0-7 used
    f4 pa = {0.f, 0.f, 0.f, 0.f};
#pragma unroll
    for (int ks = 0; ks < 4; ++ks) {
      const int row = l15;
      h8 a = *(const h8*)(xws + row * 256 + ((ks * 64 + l4 * 16) ^ ((row & 7) << 4)));
      pa = __builtin_amdgcn_mfma_f32_16x16x32_f16(a, bC[ks], pa, 0, 0, 0);
    }
    if (l4 < 2) {
      const int c128 = wv * 16 + l15, gam = c128 >> 5, u = c128 & 31;
#pragma unroll
      for (int e = 0; e < 4; ++e) {
        const int row = l4 * 4 + e;  // 0..7 = tt*4 + b
        pre_s[buf][row >> 2][row & 3][gam][u] = pa[e];
      }
    }
  };
  auto op_part = [&](const char* hb) {  // WGs ss<4: partials of h[row ss] @ Wo
    if (ss < BPG) {
      float acc = 0.f;
#pragma unroll
      for (int q = 0; q < 4; ++q) {
        h8 w_ = *(const h8*)(wots + nn * 1024 + ((pp * 64 + q * 16) ^ ((nn & 7) << 4)));
        h8 hv = *(const h8*)(hb + ss * 1024 + ((pp * 64 + q * 16) ^ (ss << 4)));
        acc = dot8(w_, hv, acc);
      }
      op_s[nn][pp] = acc;
    }
  };

  stage_x(0);
  __syncthreads();
  do_pregate(0);  // steps 0,1

  int cur = 0;
#pragma unroll 1
  for (int t = 0; t < Tt; ++t) {
    char* const hpg = hpub + gid * 16384 + (t & 1) * 8192;
    const char* const hc = hls[cur];
    char* const hn_ = hls[cur ^ 1];
    // ---- gate GEMM: wave's 16 cols, K=512 ---------------------------------
    {
      f4 g0 = {0.f, 0.f, 0.f, 0.f}, g1 = {0.f, 0.f, 0.f, 0.f};
#pragma unroll
      for (int ks = 0; ks < 16; ++ks) {
        const int row = l15;
        h8 a = *(const h8*)(hc + row * 1024 + ((ks * 64 + l4 * 16) ^ (row << 4)));
        if (ks & 1) g1 = __builtin_amdgcn_mfma_f32_16x16x32_f16(a, bW[ks], g1, 0, 0, 0);
        else        g0 = __builtin_amdgcn_mfma_f32_16x16x32_f16(a, bW[ks], g0, 0, 0, 0);
      }
      if (l4 == 0) {
        const int c128 = wv * 16 + l15, gam = c128 >> 5, u = c128 & 31;
#pragma unroll
        for (int e = 0; e < 4; ++e) gat_s[e][gam][u] = g0[e] + g1[e];
      }
    }
    __syncthreads();  // B1: gat_s ready
    // ---- cell update + tagged-packet publish (no ack, no flag) ------------
    if (tid < 128) {
      const int ph = (t >> 1) & 1, tt = t & 1;
      float aI = gat_s[b8][0][ml] + pre_s[ph][tt][b8][0][ml] + bI;
      float aF = gat_s[b8][1][ml] + pre_s[ph][tt][b8][1][ml] + bF;
      float aG = gat_s[b8][2][ml] + pre_s[ph][tt][b8][2][ml] + bG;
      float aO = gat_s[b8][3][ml] + pre_s[ph][tt][b8][3][ml] + bO;
      float iv = sigf(aI), fv = sigf(aF), gv = __sinf(aG), ov = sigf(aO);
      c_ = fv * c_ + iv * gv;
      float hnv = ov * __sinf(c_);
      _Float16 hf = (_Float16)hnv;
      u32 pkt = (u32)__builtin_bit_cast(unsigned short, hf) | ((u32)(t + 1) << 16);
      u32* dst = (u32*)(hpg + ((size_t)(b8 * 512 + ss * 32 + ml)) * 4);
      asm volatile("global_store_dword %0, %1, off sc0 sc1" :: "v"(dst), "v"(pkt) : "memory");
    }
    // ---- shadow (no remote deps) -----------------------------------------
    if (!(t & 1)) { if (t <= 1020) stage_x(t + 2); }
    else if (t <= 1021) do_pregate(((t + 1) >> 1) & 1);
    if (t > 0) op_part(hc);  // partials for out[t-1] from h_{t-1}
    // ---- poll own 4 packets, restage into hls[cur^1] ----------------------
    {
      const u32* sp = (const u32*)(hpg + (size_t)tid * 16);
      const u32 want = (u32)(t + 1);
      u32x4 v;
      while (true) {
        asm volatile("global_load_dwordx4 %0, %1, off sc0 sc1\ns_waitcnt vmcnt(0)"
                     : "=v"(v) : "v"(sp) : "memory");
        if ((v[0] >> 16) == want && (v[1] >> 16) == want &&
            (v[2] >> 16) == want && (v[3] >> 16) == want) break;
      }
      __builtin_amdgcn_sched_barrier(0);
      u32x2 d = {(v[0] & 0xFFFFu) | (v[1] << 16), (v[2] & 0xFFFFu) | (v[3] << 16)};
      const int b = tid >> 7, k = tid & 127;
      *(u32x2*)(hn_ + b * 1024 + ((k * 8) ^ (b << 4))) = d;
    }
    __syncthreads();  // B3: hls[cur^1] = h_t; op_s ready
    if (t > 0 && ss < BPG && tid < NS) {
      float s_ = bor;
#pragma unroll
      for (int p = 0; p < 16; ++p) s_ += op_s[tid][p];
      out[((size_t)(gid * BPG + ss) * Tt + (t - 1)) * NS + tid] = s_;
    }
    cur ^= 1;
  }
  // epilogue: out[1023] from h_1023 = hls[cur]
  op_part(hls[cur]);
  __syncthreads();
  if (ss < BPG && tid < NS) {
    float s_ = bor;
#pragma unroll
    for (int p = 0; p < 16; ++p) s_ += op_s[tid][p];
    out[((size_t)(gid * BPG + ss) * Tt + 1023) * NS + tid] = s_;
  }
}

extern "C" void kernel_launch(void* const* d_in, const int* in_sizes, int n_in,
                              void* d_out, int out_size, void* d_ws, size_t ws_size,
                              hipStream_t stream) {
  const float* x   = (const float*)d_in[0];
  const float* W1  = (const float*)d_in[1];
  const float* b1  = (const float*)d_in[2];
  const float* Wih = (const float*)d_in[3];
  const float* Whh = (const float*)d_in[4];
  const float* bl  = (const float*)d_in[5];
  const float* Wo  = (const float*)d_in[6];
  const float* bo  = (const float*)d_in[7];
  float* out = (float*)d_out;

  char* ws = (char*)d_ws;
  _Float16* Wc4   = (_Float16*)(ws);            // 512 KB
  float*    bias2 = (float*)(ws + 524288);      // 8 KB
  _Float16* Whh4  = (_Float16*)(ws + 532480);   // 2 MB
  char*     hpub  = ws + 2629632;               // 256 KB (16 gangs x 2 slots x 8KB)

  (void)hipMemsetAsync(hpub, 0, 262144, stream);  // kill stale tags (replay safety)
  k_wc<<<G4, 128, 0, stream>>>(W1, Wih, b1, bl, Wc4, bias2);
  k_whh<<<512, 256, 0, stream>>>(Whh, Whh4);
  k_scan<<<256, 512, 0, stream>>>(x, Wc4, bias2, Whh4, Wo, bo, out, hpub);
}